// Round 1
// baseline (5422.834 us; speedup 1.0000x reference)
//
#include <hip/hip_runtime.h>

#define LATENT 64

// One edge handled by 16 threads; each thread owns one float4 slice (4 floats)
// of the D=64 feature vector. Gather x[col] as float4, scatter-add into y[row]
// with 4 f32 atomics.
__global__ void spmm_atomic_kernel(const int* __restrict__ rows,
                                   const int* __restrict__ cols,
                                   const float* __restrict__ vals,
                                   const float* __restrict__ x,
                                   float* __restrict__ y,
                                   int E) {
    long long tid    = (long long)blockIdx.x * blockDim.x + threadIdx.x;
    long long total  = (long long)E * 16;
    long long stride = (long long)gridDim.x * blockDim.x;
    for (; tid < total; tid += stride) {
        int e = (int)(tid >> 4);
        int q = (int)(tid & 15);
        int r = rows[e];
        int c = cols[e];
        float v = vals[e];
        float4 xv = reinterpret_cast<const float4*>(x)[(size_t)c * 16 + q];
        float* yp = y + (size_t)r * LATENT + q * 4;
        atomicAdd(yp + 0, v * xv.x);
        atomicAdd(yp + 1, v * xv.y);
        atomicAdd(yp + 2, v * xv.z);
        atomicAdd(yp + 3, v * xv.w);
    }
}

// out = sigmoid(alpha[node]) * out - x   (in place, float4-vectorized)
__global__ void finalize_kernel(const float* __restrict__ alpha,
                                const float* __restrict__ x,
                                float* __restrict__ out,
                                int N) {
    long long tid    = (long long)blockIdx.x * blockDim.x + threadIdx.x;
    long long total  = (long long)N * 16;   // N * (64/4) float4 slices
    long long stride = (long long)gridDim.x * blockDim.x;
    for (; tid < total; tid += stride) {
        int i = (int)(tid >> 4);
        float a = 1.0f / (1.0f + __expf(-alpha[i]));
        float4 o  = reinterpret_cast<float4*>(out)[tid];
        float4 xv = reinterpret_cast<const float4*>(x)[tid];
        o.x = a * o.x - xv.x;
        o.y = a * o.y - xv.y;
        o.z = a * o.z - xv.z;
        o.w = a * o.w - xv.w;
        reinterpret_cast<float4*>(out)[tid] = o;
    }
}

extern "C" void kernel_launch(void* const* d_in, const int* in_sizes, int n_in,
                              void* d_out, int out_size, void* d_ws, size_t ws_size,
                              hipStream_t stream) {
    // setup_inputs order: t, x, alpha_train, edge_rows, edge_cols, edge_vals
    const float* x     = (const float*)d_in[1];
    const float* alpha = (const float*)d_in[2];
    const int*   rows  = (const int*)d_in[3];
    const int*   cols  = (const int*)d_in[4];
    const float* vals  = (const float*)d_in[5];

    const int N = in_sizes[2];          // 100000
    const int E = in_sizes[3];          // 3200000
    float* ax1 = (float*)d_ws;          // N * 64 floats = 25.6 MB
    float* out = (float*)d_out;         // ax2 accumulator, then final output

    const size_t feat_bytes = (size_t)N * LATENT * sizeof(float);

    // Zero both accumulators (deterministic per call; harness does not re-poison).
    hipMemsetAsync(ax1, 0, feat_bytes, stream);
    hipMemsetAsync(out, 0, feat_bytes, stream);

    const int block = 256;
    long long work = (long long)E * 16;
    int grid_spmm = (int)((work + block - 1) / block);   // ~200k blocks

    // Hop 1: ax1 = A @ x
    spmm_atomic_kernel<<<grid_spmm, block, 0, stream>>>(rows, cols, vals, x, ax1, E);
    // Hop 2: out = A @ ax1
    spmm_atomic_kernel<<<grid_spmm, block, 0, stream>>>(rows, cols, vals, ax1, out, E);

    // Epilogue: out = sigmoid(alpha) * out - x
    long long fwork = (long long)N * 16;
    int grid_fin = (int)((fwork + block - 1) / block);
    finalize_kernel<<<grid_fin, block, 0, stream>>>(alpha, x, out, N);
}

// Round 2
// 642.618 us; speedup vs baseline: 8.4387x; 8.4387x over previous
//
#include <hip/hip_runtime.h>

#define LATENT 64

// ---------------------------------------------------------------------------
// Counting-sort (CSR build) kernels
// ---------------------------------------------------------------------------

__global__ void histogram_kernel(const int* __restrict__ rows, int* __restrict__ cnt, int E) {
    int e = blockIdx.x * blockDim.x + threadIdx.x;
    if (e < E) atomicAdd(&cnt[rows[e]], 1);
}

// Per-256-chunk sums of cnt -> bsum[nblk]
__global__ void block_sum_kernel(const int* __restrict__ cnt, int* __restrict__ bsum, int N) {
    __shared__ int s[256];
    int t = threadIdx.x;
    int i = blockIdx.x * 256 + t;
    s[t] = (i < N) ? cnt[i] : 0;
    __syncthreads();
    for (int o = 128; o > 0; o >>= 1) {
        if (t < o) s[t] += s[t + o];
        __syncthreads();
    }
    if (t == 0) bsum[blockIdx.x] = s[0];
}

// Exclusive scan of bsum (nblk <= 512), single block of 512 threads.
__global__ void scan_partials_kernel(int* __restrict__ bsum, int nblk) {
    __shared__ int s[512];
    int t = threadIdx.x;
    int v = (t < nblk) ? bsum[t] : 0;
    s[t] = v;
    __syncthreads();
    for (int o = 1; o < 512; o <<= 1) {
        int u = (t >= o) ? s[t - o] : 0;
        __syncthreads();
        s[t] += u;
        __syncthreads();
    }
    if (t < nblk) bsum[t] = s[t] - v;   // exclusive
}

// Exclusive scan within each 256-chunk + add block prefix -> off, cursor
__global__ void chunk_scan_kernel(const int* __restrict__ cnt, const int* __restrict__ bsum,
                                  int* __restrict__ off, int* __restrict__ cursor, int N) {
    __shared__ int s[256];
    int t = threadIdx.x;
    int i = blockIdx.x * 256 + t;
    int v = (i < N) ? cnt[i] : 0;
    s[t] = v;
    __syncthreads();
    for (int o = 1; o < 256; o <<= 1) {
        int u = (t >= o) ? s[t - o] : 0;
        __syncthreads();
        s[t] += u;
        __syncthreads();
    }
    if (i < N) {
        int excl = s[t] - v + bsum[blockIdx.x];
        off[i] = excl;
        cursor[i] = excl;
    }
}

__global__ void scatter_kernel(const int* __restrict__ rows, const int* __restrict__ cols,
                               const float* __restrict__ vals, int* __restrict__ cursor,
                               int* __restrict__ scol, float* __restrict__ sval, int E) {
    int e = blockIdx.x * blockDim.x + threadIdx.x;
    if (e < E) {
        int r = rows[e];
        int p = atomicAdd(&cursor[r], 1);
        scol[p] = cols[e];
        sval[p] = vals[e];
    }
}

// ---------------------------------------------------------------------------
// Gather SpMM: one 64-lane wave per output row; lane = feature index.
// ---------------------------------------------------------------------------

__global__ void spmm_gather_kernel(const int* __restrict__ off, const int* __restrict__ cnt,
                                   const int* __restrict__ scol, const float* __restrict__ sval,
                                   const float* __restrict__ x, float* __restrict__ y, int N) {
    int wid = blockIdx.x * (blockDim.x >> 6) + (threadIdx.x >> 6);
    int lane = threadIdx.x & 63;
    if (wid >= N) return;
    int e = off[wid];
    int end = e + cnt[wid];
    float acc = 0.f;
    for (; e + 4 <= end; e += 4) {
        int c0 = scol[e], c1 = scol[e + 1], c2 = scol[e + 2], c3 = scol[e + 3];
        float v0 = sval[e], v1 = sval[e + 1], v2 = sval[e + 2], v3 = sval[e + 3];
        acc += v0 * x[(size_t)c0 * LATENT + lane];
        acc += v1 * x[(size_t)c1 * LATENT + lane];
        acc += v2 * x[(size_t)c2 * LATENT + lane];
        acc += v3 * x[(size_t)c3 * LATENT + lane];
    }
    for (; e < end; ++e) acc += sval[e] * x[(size_t)scol[e] * LATENT + lane];
    y[(size_t)wid * LATENT + lane] = acc;
}

// Hop 2 fused with epilogue: out = sigmoid(alpha[row]) * (A@ax1)[row] - x[row]
__global__ void spmm_gather_fused_kernel(const int* __restrict__ off, const int* __restrict__ cnt,
                                         const int* __restrict__ scol, const float* __restrict__ sval,
                                         const float* __restrict__ ax1,
                                         const float* __restrict__ alpha,
                                         const float* __restrict__ x,
                                         float* __restrict__ out, int N) {
    int wid = blockIdx.x * (blockDim.x >> 6) + (threadIdx.x >> 6);
    int lane = threadIdx.x & 63;
    if (wid >= N) return;
    int e = off[wid];
    int end = e + cnt[wid];
    float acc = 0.f;
    for (; e + 4 <= end; e += 4) {
        int c0 = scol[e], c1 = scol[e + 1], c2 = scol[e + 2], c3 = scol[e + 3];
        float v0 = sval[e], v1 = sval[e + 1], v2 = sval[e + 2], v3 = sval[e + 3];
        acc += v0 * ax1[(size_t)c0 * LATENT + lane];
        acc += v1 * ax1[(size_t)c1 * LATENT + lane];
        acc += v2 * ax1[(size_t)c2 * LATENT + lane];
        acc += v3 * ax1[(size_t)c3 * LATENT + lane];
    }
    for (; e < end; ++e) acc += sval[e] * ax1[(size_t)scol[e] * LATENT + lane];
    float a = 1.0f / (1.0f + __expf(-alpha[wid]));
    out[(size_t)wid * LATENT + lane] = a * acc - x[(size_t)wid * LATENT + lane];
}

// ---------------------------------------------------------------------------
// Fallback (round-1 atomic path) in case ws_size is too small for CSR build
// ---------------------------------------------------------------------------

__global__ void spmm_atomic_kernel(const int* __restrict__ rows, const int* __restrict__ cols,
                                   const float* __restrict__ vals, const float* __restrict__ x,
                                   float* __restrict__ y, int E) {
    long long tid = (long long)blockIdx.x * blockDim.x + threadIdx.x;
    long long total = (long long)E * 16;
    long long stride = (long long)gridDim.x * blockDim.x;
    for (; tid < total; tid += stride) {
        int e = (int)(tid >> 4);
        int q = (int)(tid & 15);
        int r = rows[e];
        int c = cols[e];
        float v = vals[e];
        float4 xv = reinterpret_cast<const float4*>(x)[(size_t)c * 16 + q];
        float* yp = y + (size_t)r * LATENT + q * 4;
        atomicAdd(yp + 0, v * xv.x);
        atomicAdd(yp + 1, v * xv.y);
        atomicAdd(yp + 2, v * xv.z);
        atomicAdd(yp + 3, v * xv.w);
    }
}

__global__ void finalize_kernel(const float* __restrict__ alpha, const float* __restrict__ x,
                                float* __restrict__ out, int N) {
    long long tid = (long long)blockIdx.x * blockDim.x + threadIdx.x;
    long long total = (long long)N * 16;
    long long stride = (long long)gridDim.x * blockDim.x;
    for (; tid < total; tid += stride) {
        int i = (int)(tid >> 4);
        float a = 1.0f / (1.0f + __expf(-alpha[i]));
        float4 o = reinterpret_cast<float4*>(out)[tid];
        float4 xv = reinterpret_cast<const float4*>(x)[tid];
        o.x = a * o.x - xv.x;
        o.y = a * o.y - xv.y;
        o.z = a * o.z - xv.z;
        o.w = a * o.w - xv.w;
        reinterpret_cast<float4*>(out)[tid] = o;
    }
}

// ---------------------------------------------------------------------------

extern "C" void kernel_launch(void* const* d_in, const int* in_sizes, int n_in,
                              void* d_out, int out_size, void* d_ws, size_t ws_size,
                              hipStream_t stream) {
    // setup_inputs order: t, x, alpha_train, edge_rows, edge_cols, edge_vals
    const float* x     = (const float*)d_in[1];
    const float* alpha = (const float*)d_in[2];
    const int*   rows  = (const int*)d_in[3];
    const int*   cols  = (const int*)d_in[4];
    const float* vals  = (const float*)d_in[5];

    const int N = in_sizes[2];   // 100000
    const int E = in_sizes[3];   // 3200000
    float* out = (float*)d_out;

    // Workspace layout (all 256B-aligned)
    auto align256 = [](size_t v) { return (v + 255) & ~(size_t)255; };
    size_t o_ax1  = 0;
    size_t o_scol = align256(o_ax1 + (size_t)N * LATENT * sizeof(float));
    size_t o_sval = align256(o_scol + (size_t)E * sizeof(int));
    size_t o_cnt  = align256(o_sval + (size_t)E * sizeof(float));
    size_t o_off  = align256(o_cnt + (size_t)N * sizeof(int));
    size_t o_cur  = align256(o_off + (size_t)N * sizeof(int));
    size_t o_bsum = align256(o_cur + (size_t)N * sizeof(int));
    size_t needed = o_bsum + 512 * sizeof(int);

    const int block = 256;
    const int nblk_N = (N + 255) / 256;          // 391 for N=100000

    if (ws_size >= needed && nblk_N <= 512) {
        char* ws = (char*)d_ws;
        float* ax1   = (float*)(ws + o_ax1);
        int*   scol  = (int*)(ws + o_scol);
        float* sval  = (float*)(ws + o_sval);
        int*   cnt   = (int*)(ws + o_cnt);
        int*   off   = (int*)(ws + o_off);
        int*   cur   = (int*)(ws + o_cur);
        int*   bsum  = (int*)(ws + o_bsum);

        // --- CSR build (counting sort) ---
        hipMemsetAsync(cnt, 0, (size_t)N * sizeof(int), stream);
        int grid_E = (E + block - 1) / block;
        histogram_kernel<<<grid_E, block, 0, stream>>>(rows, cnt, E);
        block_sum_kernel<<<nblk_N, 256, 0, stream>>>(cnt, bsum, N);
        scan_partials_kernel<<<1, 512, 0, stream>>>(bsum, nblk_N);
        chunk_scan_kernel<<<nblk_N, 256, 0, stream>>>(cnt, bsum, off, cur, N);
        scatter_kernel<<<grid_E, block, 0, stream>>>(rows, cols, vals, cur, scol, sval, E);

        // --- Two gather hops (one wave per row, 4 waves per block) ---
        int rows_per_block = block / 64;
        int grid_rows = (N + rows_per_block - 1) / rows_per_block;
        spmm_gather_kernel<<<grid_rows, block, 0, stream>>>(off, cnt, scol, sval, x, ax1, N);
        spmm_gather_fused_kernel<<<grid_rows, block, 0, stream>>>(off, cnt, scol, sval, ax1,
                                                                  alpha, x, out, N);
    } else {
        // Fallback: atomic scatter path
        float* ax1 = (float*)d_ws;
        const size_t feat_bytes = (size_t)N * LATENT * sizeof(float);
        hipMemsetAsync(ax1, 0, feat_bytes, stream);
        hipMemsetAsync(out, 0, feat_bytes, stream);
        long long work = (long long)E * 16;
        int grid_spmm = (int)((work + block - 1) / block);
        spmm_atomic_kernel<<<grid_spmm, block, 0, stream>>>(rows, cols, vals, x, ax1, E);
        spmm_atomic_kernel<<<grid_spmm, block, 0, stream>>>(rows, cols, vals, ax1, out, E);
        long long fwork = (long long)N * 16;
        int grid_fin = (int)((fwork + block - 1) / block);
        finalize_kernel<<<grid_fin, block, 0, stream>>>(alpha, x, out, N);
    }
}

// Round 3
// 620.478 us; speedup vs baseline: 8.7398x; 1.0357x over previous
//
#include <hip/hip_runtime.h>

#define LATENT 64

// ---------------------------------------------------------------------------
// Counting-sort (CSR build) kernels
// ---------------------------------------------------------------------------

__global__ void histogram_kernel(const int* __restrict__ rows, int* __restrict__ cnt, int E) {
    int e = blockIdx.x * blockDim.x + threadIdx.x;
    if (e < E) atomicAdd(&cnt[rows[e]], 1);
}

// Per-256-chunk sums of cnt -> bsum[nblk]
__global__ void block_sum_kernel(const int* __restrict__ cnt, int* __restrict__ bsum, int N) {
    __shared__ int s[256];
    int t = threadIdx.x;
    int i = blockIdx.x * 256 + t;
    s[t] = (i < N) ? cnt[i] : 0;
    __syncthreads();
    for (int o = 128; o > 0; o >>= 1) {
        if (t < o) s[t] += s[t + o];
        __syncthreads();
    }
    if (t == 0) bsum[blockIdx.x] = s[0];
}

// Exclusive scan of bsum (nblk <= 512), single block of 512 threads.
__global__ void scan_partials_kernel(int* __restrict__ bsum, int nblk) {
    __shared__ int s[512];
    int t = threadIdx.x;
    int v = (t < nblk) ? bsum[t] : 0;
    s[t] = v;
    __syncthreads();
    for (int o = 1; o < 512; o <<= 1) {
        int u = (t >= o) ? s[t - o] : 0;
        __syncthreads();
        s[t] += u;
        __syncthreads();
    }
    if (t < nblk) bsum[t] = s[t] - v;   // exclusive
}

// Exclusive scan within each 256-chunk + add block prefix -> off, cursor
__global__ void chunk_scan_kernel(const int* __restrict__ cnt, const int* __restrict__ bsum,
                                  int* __restrict__ off, int* __restrict__ cursor, int N) {
    __shared__ int s[256];
    int t = threadIdx.x;
    int i = blockIdx.x * 256 + t;
    int v = (i < N) ? cnt[i] : 0;
    s[t] = v;
    __syncthreads();
    for (int o = 1; o < 256; o <<= 1) {
        int u = (t >= o) ? s[t - o] : 0;
        __syncthreads();
        s[t] += u;
        __syncthreads();
    }
    if (i < N) {
        int excl = s[t] - v + bsum[blockIdx.x];
        off[i] = excl;
        cursor[i] = excl;
    }
}

// One fused 8B payload per edge: {col, val_bits}
__global__ void scatter_kernel(const int* __restrict__ rows, const int* __restrict__ cols,
                               const float* __restrict__ vals, int* __restrict__ cursor,
                               int2* __restrict__ spair, int E) {
    int e = blockIdx.x * blockDim.x + threadIdx.x;
    if (e < E) {
        int r = rows[e];
        int p = atomicAdd(&cursor[r], 1);
        spair[p] = make_int2(cols[e], __float_as_int(vals[e]));
    }
}

// ---------------------------------------------------------------------------
// Gather SpMM: one 64-lane wave per output row; lane = feature index.
// ---------------------------------------------------------------------------

__global__ void spmm_gather_kernel(const int* __restrict__ off, const int* __restrict__ cnt,
                                   const int2* __restrict__ spair,
                                   const float* __restrict__ x, float* __restrict__ y, int N) {
    int wid = blockIdx.x * (blockDim.x >> 6) + (threadIdx.x >> 6);
    int lane = threadIdx.x & 63;
    if (wid >= N) return;
    int e = off[wid];
    int end = e + cnt[wid];
    float acc = 0.f;
    for (; e + 8 <= end; e += 8) {
        int2 p0 = spair[e], p1 = spair[e + 1], p2 = spair[e + 2], p3 = spair[e + 3];
        int2 p4 = spair[e + 4], p5 = spair[e + 5], p6 = spair[e + 6], p7 = spair[e + 7];
        acc += __int_as_float(p0.y) * x[(size_t)p0.x * LATENT + lane];
        acc += __int_as_float(p1.y) * x[(size_t)p1.x * LATENT + lane];
        acc += __int_as_float(p2.y) * x[(size_t)p2.x * LATENT + lane];
        acc += __int_as_float(p3.y) * x[(size_t)p3.x * LATENT + lane];
        acc += __int_as_float(p4.y) * x[(size_t)p4.x * LATENT + lane];
        acc += __int_as_float(p5.y) * x[(size_t)p5.x * LATENT + lane];
        acc += __int_as_float(p6.y) * x[(size_t)p6.x * LATENT + lane];
        acc += __int_as_float(p7.y) * x[(size_t)p7.x * LATENT + lane];
    }
    for (; e < end; ++e) {
        int2 p = spair[e];
        acc += __int_as_float(p.y) * x[(size_t)p.x * LATENT + lane];
    }
    y[(size_t)wid * LATENT + lane] = acc;
}

// Hop 2 fused with epilogue: out = sigmoid(alpha[row]) * (A@ax1)[row] - x[row]
__global__ void spmm_gather_fused_kernel(const int* __restrict__ off, const int* __restrict__ cnt,
                                         const int2* __restrict__ spair,
                                         const float* __restrict__ ax1,
                                         const float* __restrict__ alpha,
                                         const float* __restrict__ x,
                                         float* __restrict__ out, int N) {
    int wid = blockIdx.x * (blockDim.x >> 6) + (threadIdx.x >> 6);
    int lane = threadIdx.x & 63;
    if (wid >= N) return;
    int e = off[wid];
    int end = e + cnt[wid];
    float acc = 0.f;
    for (; e + 8 <= end; e += 8) {
        int2 p0 = spair[e], p1 = spair[e + 1], p2 = spair[e + 2], p3 = spair[e + 3];
        int2 p4 = spair[e + 4], p5 = spair[e + 5], p6 = spair[e + 6], p7 = spair[e + 7];
        acc += __int_as_float(p0.y) * ax1[(size_t)p0.x * LATENT + lane];
        acc += __int_as_float(p1.y) * ax1[(size_t)p1.x * LATENT + lane];
        acc += __int_as_float(p2.y) * ax1[(size_t)p2.x * LATENT + lane];
        acc += __int_as_float(p3.y) * ax1[(size_t)p3.x * LATENT + lane];
        acc += __int_as_float(p4.y) * ax1[(size_t)p4.x * LATENT + lane];
        acc += __int_as_float(p5.y) * ax1[(size_t)p5.x * LATENT + lane];
        acc += __int_as_float(p6.y) * ax1[(size_t)p6.x * LATENT + lane];
        acc += __int_as_float(p7.y) * ax1[(size_t)p7.x * LATENT + lane];
    }
    for (; e < end; ++e) {
        int2 p = spair[e];
        acc += __int_as_float(p.y) * ax1[(size_t)p.x * LATENT + lane];
    }
    float a = 1.0f / (1.0f + __expf(-alpha[wid]));
    out[(size_t)wid * LATENT + lane] = a * acc - x[(size_t)wid * LATENT + lane];
}

// ---------------------------------------------------------------------------
// Fallback (atomic path) in case ws_size is too small for CSR build
// ---------------------------------------------------------------------------

__global__ void spmm_atomic_kernel(const int* __restrict__ rows, const int* __restrict__ cols,
                                   const float* __restrict__ vals, const float* __restrict__ x,
                                   float* __restrict__ y, int E) {
    long long tid = (long long)blockIdx.x * blockDim.x + threadIdx.x;
    long long total = (long long)E * 16;
    long long stride = (long long)gridDim.x * blockDim.x;
    for (; tid < total; tid += stride) {
        int e = (int)(tid >> 4);
        int q = (int)(tid & 15);
        int r = rows[e];
        int c = cols[e];
        float v = vals[e];
        float4 xv = reinterpret_cast<const float4*>(x)[(size_t)c * 16 + q];
        float* yp = y + (size_t)r * LATENT + q * 4;
        atomicAdd(yp + 0, v * xv.x);
        atomicAdd(yp + 1, v * xv.y);
        atomicAdd(yp + 2, v * xv.z);
        atomicAdd(yp + 3, v * xv.w);
    }
}

__global__ void finalize_kernel(const float* __restrict__ alpha, const float* __restrict__ x,
                                float* __restrict__ out, int N) {
    long long tid = (long long)blockIdx.x * blockDim.x + threadIdx.x;
    long long total = (long long)N * 16;
    long long stride = (long long)gridDim.x * blockDim.x;
    for (; tid < total; tid += stride) {
        int i = (int)(tid >> 4);
        float a = 1.0f / (1.0f + __expf(-alpha[i]));
        float4 o = reinterpret_cast<float4*>(out)[tid];
        float4 xv = reinterpret_cast<const float4*>(x)[tid];
        o.x = a * o.x - xv.x;
        o.y = a * o.y - xv.y;
        o.z = a * o.z - xv.z;
        o.w = a * o.w - xv.w;
        reinterpret_cast<float4*>(out)[tid] = o;
    }
}

// ---------------------------------------------------------------------------

extern "C" void kernel_launch(void* const* d_in, const int* in_sizes, int n_in,
                              void* d_out, int out_size, void* d_ws, size_t ws_size,
                              hipStream_t stream) {
    // setup_inputs order: t, x, alpha_train, edge_rows, edge_cols, edge_vals
    const float* x     = (const float*)d_in[1];
    const float* alpha = (const float*)d_in[2];
    const int*   rows  = (const int*)d_in[3];
    const int*   cols  = (const int*)d_in[4];
    const float* vals  = (const float*)d_in[5];

    const int N = in_sizes[2];   // 100000
    const int E = in_sizes[3];   // 3200000
    float* out = (float*)d_out;

    // Workspace layout (all 256B-aligned)
    auto align256 = [](size_t v) { return (v + 255) & ~(size_t)255; };
    size_t o_ax1   = 0;
    size_t o_spair = align256(o_ax1 + (size_t)N * LATENT * sizeof(float));
    size_t o_cnt   = align256(o_spair + (size_t)E * sizeof(int2));
    size_t o_off   = align256(o_cnt + (size_t)N * sizeof(int));
    size_t o_cur   = align256(o_off + (size_t)N * sizeof(int));
    size_t o_bsum  = align256(o_cur + (size_t)N * sizeof(int));
    size_t needed  = o_bsum + 512 * sizeof(int);

    const int block = 256;
    const int nblk_N = (N + 255) / 256;          // 391 for N=100000

    if (ws_size >= needed && nblk_N <= 512) {
        char* ws = (char*)d_ws;
        float* ax1   = (float*)(ws + o_ax1);
        int2*  spair = (int2*)(ws + o_spair);
        int*   cnt   = (int*)(ws + o_cnt);
        int*   off   = (int*)(ws + o_off);
        int*   cur   = (int*)(ws + o_cur);
        int*   bsum  = (int*)(ws + o_bsum);

        // --- CSR build (counting sort) ---
        hipMemsetAsync(cnt, 0, (size_t)N * sizeof(int), stream);
        int grid_E = (E + block - 1) / block;
        histogram_kernel<<<grid_E, block, 0, stream>>>(rows, cnt, E);
        block_sum_kernel<<<nblk_N, 256, 0, stream>>>(cnt, bsum, N);
        scan_partials_kernel<<<1, 512, 0, stream>>>(bsum, nblk_N);
        chunk_scan_kernel<<<nblk_N, 256, 0, stream>>>(cnt, bsum, off, cur, N);
        scatter_kernel<<<grid_E, block, 0, stream>>>(rows, cols, vals, cur, spair, E);

        // --- Two gather hops (one wave per row, 4 waves per block) ---
        int rows_per_block = block / 64;
        int grid_rows = (N + rows_per_block - 1) / rows_per_block;
        spmm_gather_kernel<<<grid_rows, block, 0, stream>>>(off, cnt, spair, x, ax1, N);
        spmm_gather_fused_kernel<<<grid_rows, block, 0, stream>>>(off, cnt, spair, ax1,
                                                                  alpha, x, out, N);
    } else {
        // Fallback: atomic scatter path
        float* ax1 = (float*)d_ws;
        const size_t feat_bytes = (size_t)N * LATENT * sizeof(float);
        hipMemsetAsync(ax1, 0, feat_bytes, stream);
        hipMemsetAsync(out, 0, feat_bytes, stream);
        long long work = (long long)E * 16;
        int grid_spmm = (int)((work + block - 1) / block);
        spmm_atomic_kernel<<<grid_spmm, block, 0, stream>>>(rows, cols, vals, x, ax1, E);
        spmm_atomic_kernel<<<grid_spmm, block, 0, stream>>>(rows, cols, vals, ax1, out, E);
        long long fwork = (long long)N * 16;
        int grid_fin = (int)((fwork + block - 1) / block);
        finalize_kernel<<<grid_fin, block, 0, stream>>>(alpha, x, out, N);
    }
}